// Round 1
// baseline (383.689 us; speedup 1.0000x reference)
//
#include <hip/hip_runtime.h>

typedef _Float16 half8 __attribute__((ext_vector_type(8)));
typedef float floatx4 __attribute__((ext_vector_type(4)));

#define K_ 3
#define N_ 16384
#define M_ 4096
#define D_ 128
#define H_ 64

// workspace layout (bytes)
#define OFF_FXH 0
#define SZ_FXH (K_*N_*H_*2)
#define OFF_FZH (OFF_FXH + SZ_FXH)
#define SZ_FZH (K_*M_*H_*2)
#define OFF_NXS (OFF_FZH + SZ_FZH)
#define SZ_NXS (K_*N_*4)
#define OFF_NZS (OFF_NXS + SZ_NXS)
#define SZ_NZS (K_*M_*4)
#define OFF_W1T (OFF_NZS + SZ_NZS)
#define SZ_W1T (K_*D_*H_*4)
#define OFF_W2T (OFF_W1T + SZ_W1T)
#define SZ_W2T (K_*H_*H_*4)
#define OFF_W3T (OFF_W2T + SZ_W2T)

// ---------------- weight transpose (tiny) ----------------
__global__ void transpose_w(const float* __restrict__ W1,
                            const float* __restrict__ W2,
                            const float* __restrict__ W3,
                            float* __restrict__ W1t,
                            float* __restrict__ W2t,
                            float* __restrict__ W3t) {
  int idx = blockIdx.x * 256 + threadIdx.x;
  if (idx < K_*H_*D_) {   // W1[k][h][d] -> W1t[k][d][h]
    int k = idx / (H_*D_); int r = idx % (H_*D_);
    int h = r / D_; int d = r % D_;
    W1t[k*(D_*H_) + d*H_ + h] = W1[idx];
  }
  if (idx < K_*H_*H_) {   // W2[k][g][h] -> W2t[k][h][g]; same for W3
    int k = idx / (H_*H_); int r = idx % (H_*H_);
    int g = r / H_; int h = r % H_;
    W2t[k*(H_*H_) + h*H_ + g] = W2[idx];
    W3t[k*(H_*H_) + h*H_ + g] = W3[idx];
  }
}

// ---------------- phi: fused 3-layer MLP, fp32, scale + fp16 round + norms ----------------
__device__ __forceinline__ float softplus_f(float x) {
  float p = exp2f(x * 1.44269504089f);
  float r = 0.693147180560f * log2f(1.0f + p);
  return (x > 20.0f) ? x : r;
}

__global__ __launch_bounds__(256) void phi_kernel(
    const float* __restrict__ x, const float* __restrict__ z,
    const float* __restrict__ W1t, const float* __restrict__ b1,
    const float* __restrict__ W2t, const float* __restrict__ b2,
    const float* __restrict__ W3t, const float* __restrict__ b3,
    const float* __restrict__ log_sigma,
    _Float16* __restrict__ fxh, float* __restrict__ nxs,
    _Float16* __restrict__ fzh, float* __restrict__ nzs)
{
  __shared__ float hbuf[64*68];   // 64 rows x 64 h, pad to 68
  __shared__ float nred[64*4];

  const int which = blockIdx.z;   // 0 -> x, 1 -> z
  const int nrows = which ? M_ : N_;
  if (blockIdx.x * 64 >= nrows) return;
  const float* __restrict__ src = which ? z : x;
  _Float16* __restrict__ dsth = which ? fzh : fxh;
  float* __restrict__ dstn = which ? nzs : nxs;

  const int t = threadIdx.x;
  const int lane = t & 63;
  const int wv = __builtin_amdgcn_readfirstlane(t >> 6); // wave id, uniform -> scalar weight loads
  const int k = blockIdx.y;
  const int row = blockIdx.x * 64 + lane;
  const int h0 = wv * 16;

  const float* __restrict__ w1 = W1t + k*(D_*H_);
  const float* __restrict__ w2 = W2t + k*(H_*H_);
  const float* __restrict__ w3 = W3t + k*(H_*H_);

  float acc[16];
  // ---- layer 1: D=128 -> 16 outputs of H
  #pragma unroll
  for (int i=0;i<16;i++) acc[i] = b1[k*H_ + h0 + i];
  const float4* __restrict__ xr = (const float4*)(src + (size_t)row * D_);
  #pragma unroll 2
  for (int d4=0; d4<D_/4; d4++) {
    float4 xv = xr[d4];
    const float* wd = w1 + d4*4*H_ + h0;
    #pragma unroll
    for (int i=0;i<16;i++) acc[i] = fmaf(xv.x, wd[i], acc[i]);
    #pragma unroll
    for (int i=0;i<16;i++) acc[i] = fmaf(xv.y, wd[H_+i], acc[i]);
    #pragma unroll
    for (int i=0;i<16;i++) acc[i] = fmaf(xv.z, wd[2*H_+i], acc[i]);
    #pragma unroll
    for (int i=0;i<16;i++) acc[i] = fmaf(xv.w, wd[3*H_+i], acc[i]);
  }
  #pragma unroll
  for (int i=0;i<16;i+=4) {
    float4 v;
    v.x = softplus_f(acc[i+0]); v.y = softplus_f(acc[i+1]);
    v.z = softplus_f(acc[i+2]); v.w = softplus_f(acc[i+3]);
    *(float4*)&hbuf[lane*68 + h0 + i] = v;
  }
  __syncthreads();
  // ---- layer 2
  #pragma unroll
  for (int i=0;i<16;i++) acc[i] = b2[k*H_ + h0 + i];
  #pragma unroll 2
  for (int h4=0; h4<H_/4; h4++) {
    float4 hv = *(const float4*)&hbuf[lane*68 + h4*4];
    const float* wd = w2 + h4*4*H_ + h0;
    #pragma unroll
    for (int i=0;i<16;i++) acc[i] = fmaf(hv.x, wd[i], acc[i]);
    #pragma unroll
    for (int i=0;i<16;i++) acc[i] = fmaf(hv.y, wd[H_+i], acc[i]);
    #pragma unroll
    for (int i=0;i<16;i++) acc[i] = fmaf(hv.z, wd[2*H_+i], acc[i]);
    #pragma unroll
    for (int i=0;i<16;i++) acc[i] = fmaf(hv.w, wd[3*H_+i], acc[i]);
  }
  __syncthreads();  // all reads of h1 done
  #pragma unroll
  for (int i=0;i<16;i+=4) {
    float4 v;
    v.x = softplus_f(acc[i+0]); v.y = softplus_f(acc[i+1]);
    v.z = softplus_f(acc[i+2]); v.w = softplus_f(acc[i+3]);
    *(float4*)&hbuf[lane*68 + h0 + i] = v;
  }
  __syncthreads();
  // ---- layer 3 (no activation)
  #pragma unroll
  for (int i=0;i<16;i++) acc[i] = b3[k*H_ + h0 + i];
  #pragma unroll 2
  for (int h4=0; h4<H_/4; h4++) {
    float4 hv = *(const float4*)&hbuf[lane*68 + h4*4];
    const float* wd = w3 + h4*4*H_ + h0;
    #pragma unroll
    for (int i=0;i<16;i++) acc[i] = fmaf(hv.x, wd[i], acc[i]);
    #pragma unroll
    for (int i=0;i<16;i++) acc[i] = fmaf(hv.y, wd[H_+i], acc[i]);
    #pragma unroll
    for (int i=0;i<16;i++) acc[i] = fmaf(hv.z, wd[2*H_+i], acc[i]);
    #pragma unroll
    for (int i=0;i<16;i++) acc[i] = fmaf(hv.w, wd[3*H_+i], acc[i]);
  }
  // ---- scale by sqrt(c2_k), round to fp16, norms from ROUNDED values
  float lsv = log_sigma[k];
  float inv2sig = 0.5f * exp2f(-lsv * 3.32192809489f);  // 1/(2*10^ls)
  float c2 = inv2sig * 1.44269504089f;                  // * log2(e)
  float s = sqrtf(c2);
  half8 u0, u1;
  float nsum = 0.f;
  #pragma unroll
  for (int i=0;i<8;i++) {
    _Float16 v = (_Float16)(s * acc[i]);
    u0[i] = v; float f = (float)v; nsum = fmaf(f, f, nsum);
  }
  #pragma unroll
  for (int i=0;i<8;i++) {
    _Float16 v = (_Float16)(s * acc[8+i]);
    u1[i] = v; float f = (float)v; nsum = fmaf(f, f, nsum);
  }
  _Float16* dp = dsth + ((size_t)k*nrows + row)*H_ + h0;
  *(half8*)dp = u0;
  *(half8*)(dp + 8) = u1;
  nred[lane*4 + wv] = nsum;
  __syncthreads();
  if (t < 64) {
    float v = nred[t*4+0] + nred[t*4+1] + nred[t*4+2] + nred[t*4+3];
    dstn[(size_t)k*nrows + row] = v;
  }
}

// ---------------- main: fused MFMA dot + exp + weighted sum ----------------
__global__ __launch_bounds__(256, 2) void dkef_main(
    const _Float16* __restrict__ fxh, const _Float16* __restrict__ fzh,
    const float* __restrict__ nxs, const float* __restrict__ nzs,
    const float* __restrict__ kw, float* __restrict__ out)
{
  __shared__ __align__(16) _Float16 Ab[128*72];  // 128 n-rows x 64 h, pad 72
  __shared__ __align__(16) _Float16 Bb[128*72];  // 128 m-rows x 64 h
  __shared__ float nxl[128];
  __shared__ float nzl[128];

  const int t = threadIdx.x;
  const int lane = t & 63;
  const int wv = t >> 6;
  const int m0 = blockIdx.x * 128;
  const int n0 = blockIdx.y * 128;

  // softmax over kernel_weights (3 values), computed redundantly per thread
  float k0 = kw[0], k1 = kw[1], k2 = kw[2];
  float mx = fmaxf(k0, fmaxf(k1, k2));
  float e0 = exp2f((k0 - mx) * 1.44269504089f);
  float e1 = exp2f((k1 - mx) * 1.44269504089f);
  float e2 = exp2f((k2 - mx) * 1.44269504089f);
  float winv = 1.0f / (e0 + e1 + e2);
  float wk3[3] = {e0 * winv, e1 * winv, e2 * winv};

  const int wa = (wv >> 1) * 64;   // n-half within block tile
  const int wb = (wv & 1) * 64;    // m-half
  const int fr = lane & 15;        // frag row/col
  const int fq = lane >> 4;        // quad

  floatx4 oacc[4][4] = {};

  for (int k = 0; k < K_; k++) {
    __syncthreads();   // previous iteration done reading LDS
    // stage A (fx rows) and B (fz rows): 16 KB each, int4 chunks
    {
      const int4* ga = (const int4*)(fxh + ((size_t)k*N_ + n0)*H_);
      #pragma unroll
      for (int it = 0; it < 4; it++) {
        int idx = t + it*256;
        int r = idx >> 3, c = idx & 7;
        *(int4*)&Ab[r*72 + c*8] = ga[idx];
      }
      const int4* gb = (const int4*)(fzh + ((size_t)k*M_ + m0)*H_);
      #pragma unroll
      for (int it = 0; it < 4; it++) {
        int idx = t + it*256;
        int r = idx >> 3, c = idx & 7;
        *(int4*)&Bb[r*72 + c*8] = gb[idx];
      }
      if (t < 128) nxl[t] = nxs[(size_t)k*N_ + n0 + t];
      else         nzl[t-128] = nzs[(size_t)k*M_ + m0 + (t-128)];
    }
    __syncthreads();

    // MFMA: wave computes 64x64 region = 4x4 tiles of 16x16, K=64 in 2 steps of 32
    floatx4 dacc[4][4] = {};
    #pragma unroll
    for (int ks = 0; ks < 2; ks++) {
      half8 af[4], bf[4];
      #pragma unroll
      for (int i = 0; i < 4; i++)
        af[i] = *(const half8*)&Ab[(wa + i*16 + fr)*72 + ks*32 + fq*8];
      #pragma unroll
      for (int j = 0; j < 4; j++)
        bf[j] = *(const half8*)&Bb[(wb + j*16 + fr)*72 + ks*32 + fq*8];
      #pragma unroll
      for (int i = 0; i < 4; i++)
        #pragma unroll
        for (int j = 0; j < 4; j++)
          dacc[i][j] = __builtin_amdgcn_mfma_f32_16x16x32_f16(af[i], bf[j], dacc[i][j], 0, 0, 0);
    }

    // epilogue: out += w_k * 2^min(2*dot - (nx+nz), 0)
    float wkv = wk3[k];
    #pragma unroll
    for (int i = 0; i < 4; i++) {
      floatx4 nx4 = *(const floatx4*)&nxl[wa + i*16 + fq*4];
      #pragma unroll
      for (int j = 0; j < 4; j++) {
        float nzv = nzl[wb + j*16 + fr];
        #pragma unroll
        for (int r = 0; r < 4; r++) {
          float sm = nx4[r] + nzv;
          float e = fmaf(2.0f, dacc[i][j][r], -sm);
          e = fminf(e, 0.0f);
          oacc[i][j][r] = fmaf(wkv, exp2f(e), oacc[i][j][r]);
        }
      }
    }
  }

  // store 128x128 tile
  #pragma unroll
  for (int i = 0; i < 4; i++) {
    #pragma unroll
    for (int r = 0; r < 4; r++) {
      size_t rowg = (size_t)(n0 + wa + i*16 + fq*4 + r);
      float* orow = out + rowg * M_ + m0 + wb + fr;
      #pragma unroll
      for (int j = 0; j < 4; j++) orow[j*16] = oacc[i][j][r];
    }
  }
}

extern "C" void kernel_launch(void* const* d_in, const int* in_sizes, int n_in,
                              void* d_out, int out_size, void* d_ws, size_t ws_size,
                              hipStream_t stream) {
  const float* x  = (const float*)d_in[0];
  const float* z  = (const float*)d_in[1];
  const float* W1 = (const float*)d_in[2];
  const float* b1 = (const float*)d_in[3];
  const float* W2 = (const float*)d_in[4];
  const float* b2 = (const float*)d_in[5];
  const float* W3 = (const float*)d_in[6];
  const float* b3 = (const float*)d_in[7];
  const float* ls = (const float*)d_in[8];
  const float* kw = (const float*)d_in[9];
  float* out = (float*)d_out;

  char* ws = (char*)d_ws;
  _Float16* fxh = (_Float16*)(ws + OFF_FXH);
  _Float16* fzh = (_Float16*)(ws + OFF_FZH);
  float* nxs = (float*)(ws + OFF_NXS);
  float* nzs = (float*)(ws + OFF_NZS);
  float* W1t = (float*)(ws + OFF_W1T);
  float* W2t = (float*)(ws + OFF_W2T);
  float* W3t = (float*)(ws + OFF_W3T);

  hipLaunchKernelGGL(transpose_w, dim3((K_*H_*D_ + 255)/256), dim3(256), 0, stream,
                     W1, W2, W3, W1t, W2t, W3t);
  hipLaunchKernelGGL(phi_kernel, dim3(N_/64, K_, 2), dim3(256), 0, stream,
                     x, z, W1t, b1, W2t, b2, W3t, b3, ls, fxh, nxs, fzh, nzs);
  hipLaunchKernelGGL(dkef_main, dim3(M_/128, N_/128), dim3(256), 0, stream,
                     fxh, fzh, nxs, nzs, kw, out);
}